// Round 10
// baseline (265.222 us; speedup 1.0000x reference)
//
#include <hip/hip_runtime.h>

typedef unsigned short u16;
typedef __attribute__((ext_vector_type(4))) unsigned short u16x4;
typedef __attribute__((ext_vector_type(8))) unsigned short u16x8;
typedef __attribute__((ext_vector_type(8))) __bf16 bf16x8;
typedef __attribute__((ext_vector_type(4))) float f32x4;

#define SLEN_ 2048
#define BSZ_ 8
#define NH_ 16
#define DH_ 64
#define IND_ 1024
#define MROWS_ (SLEN_*BSZ_)   // 16384
#define NQKV_ (NH_*3*DH_)     // 3072
#define NOUT_ (NH_*DH_)       // 1024
#define NT_ 16                // K-tiles of 64 (K=1024)

__device__ __forceinline__ float b2f(u16 u) {
    return __uint_as_float(((unsigned)u) << 16);
}
__device__ __forceinline__ u16 f2b(float f) {
    unsigned u = __float_as_uint(f);
    u = u + 0x7FFFu + ((u >> 16) & 1u);   // RNE
    return (u16)(u >> 16);
}

#define GLOAD_LDS16(g, l) __builtin_amdgcn_global_load_lds( \
    (const __attribute__((address_space(1))) unsigned int*)(g), \
    (__attribute__((address_space(3))) unsigned int*)(l), 16, 0, 0)

// swizzled LDS byte offset for [64][64] bf16 tiles (row stride 128 B)
#define TI(r, c) ((((r) << 7) + ((c) << 1)) ^ (((r) & 7) << 4))

// ---------------- cast fp32 weights -> bf16 ----------------
__global__ __launch_bounds__(256) void cast_weights(
        const float* __restrict__ wq, const float* __restrict__ wo,
        u16* __restrict__ wqb, u16* __restrict__ wob)
{
    int i = blockIdx.x * 256 + threadIdx.x;
    const int NQ4 = NQKV_ * IND_ / 4;
    float4 v;
    u16* dst;
    if (i < NQ4) { v = ((const float4*)wq)[i]; dst = wqb + (size_t)i * 4; }
    else { int j = i - NQ4; v = ((const float4*)wo)[j]; dst = wob + (size_t)j * 4; }
    u16x4 o;
    o[0] = f2b(v.x); o[1] = f2b(v.y); o[2] = f2b(v.z); o[3] = f2b(v.w);
    *(u16x4*)dst = o;
}

// ---------------- LayerNorm -> bf16 ----------------
__global__ __launch_bounds__(256) void ln_kernel(
        const float* __restrict__ x, const float* __restrict__ g,
        const float* __restrict__ bt, u16* __restrict__ h)
{
    int row = blockIdx.x, tid = threadIdx.x;
    const float4 v = ((const float4*)(x + (size_t)row * IND_))[tid];
    float s  = v.x + v.y + v.z + v.w;
    float s2 = v.x*v.x + v.y*v.y + v.z*v.z + v.w*v.w;
    #pragma unroll
    for (int m = 1; m < 64; m <<= 1) { s += __shfl_xor(s, m); s2 += __shfl_xor(s2, m); }
    __shared__ float sh[8];
    int w = tid >> 6, l = tid & 63;
    if (l == 0) { sh[w] = s; sh[4 + w] = s2; }
    __syncthreads();
    s  = sh[0] + sh[1] + sh[2] + sh[3];
    s2 = sh[4] + sh[5] + sh[6] + sh[7];
    float mu   = s * (1.f / IND_);
    float var  = s2 * (1.f / IND_) - mu * mu;
    float rstd = rsqrtf(var + 1e-5f);
    float4 gg = ((const float4*)g)[tid];
    float4 bb = ((const float4*)bt)[tid];
    u16x4 o;
    o[0] = f2b((v.x - mu) * rstd * gg.x + bb.x);
    o[1] = f2b((v.y - mu) * rstd * gg.y + bb.y);
    o[2] = f2b((v.z - mu) * rstd * gg.z + bb.z);
    o[3] = f2b((v.w - mu) * rstd * gg.w + bb.w);
    ((u16x4*)(h + (size_t)row * IND_))[tid] = o;
}

// ---------------- 256x256 bf16 GEMM, C[M,N] = A[M,K]*B[N,K]^T, BK=64 ----------------
// (round-5 schedule: best measured 114.5us, MfmaUtil 37%, 0 conflicts.)
// MODE 1: f32 store with += X (residual).  MODE 2: qkv epilogue -- each wave's
// 64-col quadrant is exactly one q/k/v head-section (sections are 64-aligned);
// q,k sections get elu(+1) + row-normalize ON F32 ACCS before bf16 store
// (moves the scans' serial elu+sum critical path into the GEMM epilogue).
template<int MODE>
__global__ __launch_bounds__(512, 2) void gemm256(
        const u16* __restrict__ A, const u16* __restrict__ Bm,
        u16* __restrict__ Cb, float* __restrict__ Cf, const float* __restrict__ X,
        int M, int N, int K)
{
    __shared__ char smem[131072];   // [buf][A 32KB | B 32KB]

    const int tid = threadIdx.x;
    const int w = tid >> 6, l = tid & 63;
    const int wmi = w >> 2, wni = w & 3;
    const int fr = l & 15, fq = l >> 4;

    const int h = blockIdx.y * gridDim.x + blockIdx.x;
    const int xcd = h & 7, i = h >> 3;
    const int bm = xcd * 8 + (i & 7);
    const int bn = i >> 3;

    const int sr = l >> 3;
    const int sc = ((l & 7) ^ sr) * 8;
    const u16* ga = A  + (size_t)(bm * 256 + w * 8 + sr) * K + sc;
    const u16* gb = Bm + (size_t)(bn * 256 + w * 8 + sr) * K + sc;
    char* lA = smem + w * 1024;
    char* lB = smem + 32768 + w * 1024;
    const size_t K64 = (size_t)K * 64;

#define STAGE(t, bufb) { \
    const u16* gat = ga + (t) * 64; const u16* gbt = gb + (t) * 64; \
    char* la = lA + (bufb) * 65536; char* lb = lB + (bufb) * 65536; \
    GLOAD_LDS16(gat,            la);            \
    GLOAD_LDS16(gat + K64,      la + 8192);     \
    GLOAD_LDS16(gat + 2 * K64,  la + 16384);    \
    GLOAD_LDS16(gat + 3 * K64,  la + 24576);    \
    GLOAD_LDS16(gbt,            lb);            \
    GLOAD_LDS16(gbt + K64,      lb + 8192);     \
    GLOAD_LDS16(gbt + 2 * K64,  lb + 16384);    \
    GLOAD_LDS16(gbt + 3 * K64,  lb + 24576);    \
}

    const int cswz = (fr & 7) << 4;
    const int c0 = (fq * 16) ^ cswz;
    const int c1 = (64 + fq * 16) ^ cswz;
    const char* rdA = smem + (wmi * 128 + fr) * 128;
    const char* rdB = smem + 32768 + (wni * 64 + fr) * 128;

#define RD_FRAGS(dstA, dstB, base_off, cc) { \
    const char* bA_ = rdA + (base_off); const char* bB_ = rdB + (base_off); \
    _Pragma("unroll") for (int m_ = 0; m_ < 8; m_++) \
        dstA[m_] = *(const bf16x8*)(bA_ + m_ * 2048 + (cc)); \
    _Pragma("unroll") for (int n_ = 0; n_ < 4; n_++) \
        dstB[n_] = *(const bf16x8*)(bB_ + n_ * 2048 + (cc)); \
}

#define MFMA32(srcA, srcB) { \
    _Pragma("unroll") for (int m_ = 0; m_ < 8; m_++) \
        _Pragma("unroll") for (int n_ = 0; n_ < 4; n_++) \
            acc[m_][n_] = __builtin_amdgcn_mfma_f32_16x16x32_bf16(srcA[m_], srcB[n_], acc[m_][n_], 0, 0, 0); \
}

    f32x4 acc[8][4] = {};
    bf16x8 fsA_A[8], fsA_B[4];
    bf16x8 fsB_A[8], fsB_B[4];

    STAGE(0, 0);
    STAGE(1, 1);
    asm volatile("s_waitcnt vmcnt(8)" ::: "memory");
    __builtin_amdgcn_s_barrier();
    RD_FRAGS(fsA_A, fsA_B, 0, c0);
    asm volatile("s_waitcnt lgkmcnt(0)" ::: "memory");
    __builtin_amdgcn_sched_barrier(0);

    #pragma unroll 1
    for (int t = 0; t < NT_; t++) {
        const int cur = (t & 1) * 65536;
        const int nxt = ((t + 1) & 1) * 65536;
        RD_FRAGS(fsB_A, fsB_B, cur, c1);
        __builtin_amdgcn_s_setprio(1);
        MFMA32(fsA_A, fsA_B);
        __builtin_amdgcn_s_setprio(0);
        asm volatile("s_waitcnt lgkmcnt(0)" ::: "memory");
        __builtin_amdgcn_sched_barrier(0);
        __builtin_amdgcn_s_barrier();
        if (t + 2 < NT_) STAGE(t + 2, t & 1);
        if (t < NT_ - 2) asm volatile("s_waitcnt vmcnt(8)" ::: "memory");
        else             asm volatile("s_waitcnt vmcnt(0)" ::: "memory");
        __builtin_amdgcn_s_barrier();
        if (t < NT_ - 1) RD_FRAGS(fsA_A, fsA_B, nxt, c0);
        __builtin_amdgcn_s_setprio(1);
        MFMA32(fsB_A, fsB_B);
        __builtin_amdgcn_s_setprio(0);
        asm volatile("s_waitcnt lgkmcnt(0)" ::: "memory");
        __builtin_amdgcn_sched_barrier(0);
        __builtin_amdgcn_s_barrier();
    }
#undef STAGE
#undef RD_FRAGS
#undef MFMA32

    if (MODE == 2) {
        // section type of this wave's 64-col quadrant: 0=q, 1=k, 2=v
        const int sec = (bn * 4 + wni) % 3;
        #pragma unroll
        for (int m = 0; m < 8; m++)
            #pragma unroll
            for (int r = 0; r < 4; r++) {
                int row = bm * 256 + wmi * 128 + m * 16 + fq * 4 + r;
                u16* gd = Cb + (size_t)row * N + bn * 256 + wni * 64 + fr;
                if (sec < 2) {
                    float ev[4];
                    #pragma unroll
                    for (int n = 0; n < 4; n++) {
                        float xv = acc[m][n][r];
                        ev[n] = xv > 0.f ? xv + 1.f : __expf(xv);
                    }
                    float s = ev[0] + ev[1] + ev[2] + ev[3];
                    s += __shfl_xor(s, 1); s += __shfl_xor(s, 2);
                    s += __shfl_xor(s, 4); s += __shfl_xor(s, 8);
                    float inv = 1.f / (s + 1e-5f);
                    #pragma unroll
                    for (int n = 0; n < 4; n++) gd[n * 16] = f2b(ev[n] * inv);
                } else {
                    #pragma unroll
                    for (int n = 0; n < 4; n++) gd[n * 16] = f2b(acc[m][n][r]);
                }
            }
        return;
    }

    #pragma unroll
    for (int m = 0; m < 8; m++)
        #pragma unroll
        for (int r = 0; r < 4; r++) {
            int row = bm * 256 + wmi * 128 + m * 16 + fq * 4 + r;
            #pragma unroll
            for (int n = 0; n < 4; n++) {
                int col = bn * 256 + wni * 64 + n * 16 + fr;
                size_t idx = (size_t)row * N + col;
                Cf[idx] = acc[m][n][r] + X[idx];
            }
        }
}

// ---------------- scanS: S_c = K^T V per chunk (grid 4096 = n*128 + bh) ----------------
// k,q already elu+normalized by g1's epilogue -> staging is pure bf16 copy.
__global__ __launch_bounds__(256) void scanS(
        const u16* __restrict__ qkv, u16* __restrict__ Sbuf)
{
    __shared__ u16 Kt_l[4096], Vt_l[4096];

    const int blk = blockIdx.x;
    const int bh = blk & 127, n = blk >> 7;
    const int b = bh >> 4, hh = bh & 15;
    const int tid = threadIdx.x;
    const int w = tid >> 6, l = tid & 63;
    const int fr = l & 15, fq = l >> 4;

    if (w == 0) {
        const u16* g0 = qkv + ((size_t)(n * 64 + l) * BSZ_ + b) * NQKV_ + hh * 192 + 64;
        u16x8 pre[8];
        #pragma unroll
        for (int j = 0; j < 8; j++) pre[j] = *(const u16x8*)(g0 + j * 8);
        #pragma unroll
        for (int j = 0; j < 8; j++)
            #pragma unroll
            for (int m = 0; m < 8; m++)
                *(u16*)((char*)Kt_l + TI(j * 8 + m, l)) = pre[j][m];
    } else if (w <= 2) {
        const u16* g0 = qkv + ((size_t)(n * 64 + l) * BSZ_ + b) * NQKV_ + hh * 192 + 128 + (w - 1) * 32;
        int e0 = (w - 1) * 32;
        u16x8 pre[4];
        #pragma unroll
        for (int j = 0; j < 4; j++) pre[j] = *(const u16x8*)(g0 + j * 8);
        #pragma unroll
        for (int j = 0; j < 4; j++)
            #pragma unroll
            for (int m = 0; m < 8; m++)
                *(u16*)((char*)Vt_l + TI(e0 + j * 8 + m, l)) = pre[j][m];
    }
    __syncthreads();

    f32x4 aS2[4] = {};
    bf16x8 akt[2];
    #pragma unroll
    for (int ks = 0; ks < 2; ks++)
        akt[ks] = *(const bf16x8*)((const char*)Kt_l + TI(w * 16 + fr, ks * 32 + fq * 8));
    #pragma unroll
    for (int jt = 0; jt < 4; jt++)
        #pragma unroll
        for (int ks = 0; ks < 2; ks++) {
            bf16x8 bv = *(const bf16x8*)((const char*)Vt_l + TI(jt * 16 + fr, ks * 32 + fq * 8));
            aS2[jt] = __builtin_amdgcn_mfma_f32_16x16x32_bf16(akt[ks], bv, aS2[jt], 0, 0, 0);
        }

    u16* Sg = Sbuf + ((size_t)bh * 32 + n) * 4096;
    #pragma unroll
    for (int jt = 0; jt < 4; jt++)
        #pragma unroll
        for (int r = 0; r < 4; r++)
            Sg[(w * 16 + fq * 4 + r) * 64 + jt * 16 + fr] = f2b(aS2[jt][r]);
}

// ---------------- scanB: exclusive prefix over chunks (in-place bf16) ----------------
__global__ __launch_bounds__(256) void scanB(
        u16* __restrict__ Sbuf, const float* __restrict__ state, float* __restrict__ wfin)
{
    const int blk = blockIdx.x;
    const int bh = blk >> 2;
    const int e0 = (blk & 3) * 1024 + threadIdx.x * 4;
    float4 acc = *(const float4*)(state + (size_t)bh * 4096 + e0);
    u16* Sp = Sbuf + (size_t)bh * 32 * 4096 + e0;
    #pragma unroll
    for (int nn = 0; nn < 32; nn++) {
        u16x4 s = *(const u16x4*)(Sp + nn * 4096);
        u16x4 p;
        p[0] = f2b(acc.x); p[1] = f2b(acc.y); p[2] = f2b(acc.z); p[3] = f2b(acc.w);
        *(u16x4*)(Sp + nn * 4096) = p;
        acc.x += b2f(s[0]); acc.y += b2f(s[1]);
        acc.z += b2f(s[2]); acc.w += b2f(s[3]);
    }
    *(float4*)(wfin + (size_t)bh * 4096 + e0) = acc;
}

// ---------------- scanO: O = tril(K·Q^T)·V + Q·W_prefix (grid 4096) ----------------
// q,k pre-normalized -> staging is pure bf16 copy (no float math before barrier).
__global__ __launch_bounds__(256) void scanO(
        const u16* __restrict__ qkv, const u16* __restrict__ Sbuf, u16* __restrict__ obf)
{
    __shared__ u16 Q_l[4096], K_l[4096], Vt_l[4096], P_l[4096], W_l[4096];

    const int blk = blockIdx.x;
    const int bh = blk & 127, n = blk >> 7;
    const int b = bh >> 4, hh = bh & 15;
    const int tid = threadIdx.x;
    const int w = tid >> 6, l = tid & 63;
    const int fr = l & 15, fq = l >> 4;

    // staging (w0=q, w1=k, w2/w3=v halves) -- plain copies
    int goff = (w == 0) ? 0 : (w == 1) ? 64 : (w == 2) ? 128 : 160;
    const u16* g0 = qkv + ((size_t)(n * 64 + l) * BSZ_ + b) * NQKV_ + hh * 192 + goff;
    u16x8 pre[8];
    if (w < 2) {
        #pragma unroll
        for (int j = 0; j < 8; j++) pre[j] = *(const u16x8*)(g0 + j * 8);
    } else {
        #pragma unroll
        for (int j = 0; j < 4; j++) pre[j] = *(const u16x8*)(g0 + j * 8);
    }

    // W_l fill from bf16 prefix [d][e] -> swizzled [e][d] (overlaps loads)
    const u16* Wp = Sbuf + ((size_t)bh * 32 + n) * 4096;
    #pragma unroll
    for (int k2 = 0; k2 < 4; k2++) {
        int g = tid * 4 + k2 * 1024;
        u16x4 s = *(const u16x4*)(Wp + g);
        int d = g >> 6, e = g & 63;
        #pragma unroll
        for (int i2 = 0; i2 < 4; i2++)
            *(u16*)((char*)W_l + TI(e + i2, d)) = s[i2];
    }

    if (w < 2) {
        u16* dst = (w == 0) ? Q_l : K_l;
        #pragma unroll
        for (int j = 0; j < 8; j++)
            *(u16x8*)((char*)dst + TI(l, j * 8)) = pre[j];
    } else {
        int e0 = (w == 2) ? 0 : 32;
        #pragma unroll
        for (int j = 0; j < 4; j++)
            #pragma unroll
            for (int m = 0; m < 8; m++)
                *(u16*)((char*)Vt_l + TI(e0 + j * 8 + m, l)) = pre[j][m];
    }
    __syncthreads();

    // St = K·Q^T (out rows s = w*16.., cols t); masked P[t][s] -> P_l
    f32x4 aS[4] = {};
    bf16x8 aK[2];
    #pragma unroll
    for (int ks = 0; ks < 2; ks++)
        aK[ks] = *(const bf16x8*)((const char*)K_l + TI(w * 16 + fr, ks * 32 + fq * 8));
    #pragma unroll
    for (int jt = 0; jt < 4; jt++)
        #pragma unroll
        for (int ks = 0; ks < 2; ks++) {
            bf16x8 bq = *(const bf16x8*)((const char*)Q_l + TI(jt * 16 + fr, ks * 32 + fq * 8));
            aS[jt] = __builtin_amdgcn_mfma_f32_16x16x32_bf16(aK[ks], bq, aS[jt], 0, 0, 0);
        }
    #pragma unroll
    for (int jt = 0; jt < 4; jt++) {
        int t = jt * 16 + fr;
        int s0 = w * 16 + fq * 4;
        u16 e0 = (s0 + 0 <= t) ? f2b(aS[jt][0]) : (u16)0;
        u16 e1 = (s0 + 1 <= t) ? f2b(aS[jt][1]) : (u16)0;
        u16 e2 = (s0 + 2 <= t) ? f2b(aS[jt][2]) : (u16)0;
        u16 e3 = (s0 + 3 <= t) ? f2b(aS[jt][3]) : (u16)0;
        uint2 pkk;
        pkk.x = (unsigned)e0 | ((unsigned)e1 << 16);
        pkk.y = (unsigned)e2 | ((unsigned)e3 << 16);
        *(uint2*)((char*)P_l + TI(t, s0)) = pkk;
    }
    __syncthreads();

    // O = P·V + Q·W_prefix (rows t = w*16..)
    f32x4 aO[4] = {};
    bf16x8 ap[2], aq2[2];
    #pragma unroll
    for (int ks = 0; ks < 2; ks++) {
        ap[ks]  = *(const bf16x8*)((const char*)P_l + TI(w * 16 + fr, ks * 32 + fq * 8));
        aq2[ks] = *(const bf16x8*)((const char*)Q_l + TI(w * 16 + fr, ks * 32 + fq * 8));
    }
    #pragma unroll
    for (int jt = 0; jt < 4; jt++) {
        #pragma unroll
        for (int ks = 0; ks < 2; ks++) {
            bf16x8 bv = *(const bf16x8*)((const char*)Vt_l + TI(jt * 16 + fr, ks * 32 + fq * 8));
            aO[jt] = __builtin_amdgcn_mfma_f32_16x16x32_bf16(ap[ks], bv, aO[jt], 0, 0, 0);
        }
        #pragma unroll
        for (int ks = 0; ks < 2; ks++) {
            bf16x8 bw = *(const bf16x8*)((const char*)W_l + TI(jt * 16 + fr, ks * 32 + fq * 8));
            aO[jt] = __builtin_amdgcn_mfma_f32_16x16x32_bf16(aq2[ks], bw, aO[jt], 0, 0, 0);
        }
    }
    __syncthreads();

    #pragma unroll
    for (int jt = 0; jt < 4; jt++)
        #pragma unroll
        for (int r = 0; r < 4; r++)
            *(u16*)((char*)P_l + TI(w * 16 + fq * 4 + r, jt * 16 + fr)) = f2b(aO[jt][r]);
    __syncthreads();

    {
        int t = tid >> 2, seg = tid & 3;
        u16x8 o1 = *(const u16x8*)((const char*)P_l + TI(t, seg * 16));
        u16x8 o2 = *(const u16x8*)((const char*)P_l + TI(t, seg * 16 + 8));
        u16* gd = obf + ((size_t)(n * 64 + t) * BSZ_ + b) * NOUT_ + hh * 64 + seg * 16;
        *(u16x8*)(gd) = o1;
        *(u16x8*)(gd + 8) = o2;
    }
}

extern "C" void kernel_launch(void* const* d_in, const int* in_sizes, int n_in,
                              void* d_out, int out_size, void* d_ws, size_t ws_size,
                              hipStream_t stream) {
    const float* x     = (const float*)d_in[0];
    const float* state = (const float*)d_in[1];
    const float* wqkv  = (const float*)d_in[2];
    const float* wout  = (const float*)d_in[3];
    const float* gamma = (const float*)d_in[4];
    const float* beta  = (const float*)d_in[5];

    float* out0 = (float*)d_out;
    float* wfin = (float*)d_out + (size_t)MROWS_ * IND_;

    char* ws = (char*)d_ws;
    u16* qkv_bf = (u16*)ws;                                   // 96 MiB
    u16* h_bf   = (u16*)(ws + 100663296);                     // 32 MiB (o_bf reuse)
    u16* o_bf   = h_bf;
    u16* wq_bf  = (u16*)(ws + 134217728);                     // 6 MiB
    u16* wo_bf  = (u16*)(ws + 140509184);                     // 2 MiB
    u16* S_bf   = (u16*)(ws + 142606336);                     // 32 MiB (S / prefix)

    cast_weights<<<4096, 256, 0, stream>>>(wqkv, wout, wq_bf, wo_bf);
    ln_kernel<<<MROWS_, 256, 0, stream>>>(x, gamma, beta, h_bf);
    dim3 g1(MROWS_ / 256, NQKV_ / 256);   // 64 x 12 = 768 blocks
    gemm256<2><<<g1, 512, 0, stream>>>(h_bf, wq_bf, qkv_bf, nullptr, nullptr, MROWS_, NQKV_, IND_);
    scanS<<<4096, 256, 0, stream>>>(qkv_bf, S_bf);
    scanB<<<512, 256, 0, stream>>>(S_bf, state, wfin);
    scanO<<<4096, 256, 0, stream>>>(qkv_bf, S_bf, o_bf);
    dim3 g2(MROWS_ / 256, NOUT_ / 256);   // 64 x 4 = 256 blocks
    gemm256<1><<<g2, 512, 0, stream>>>(o_bf, wo_bf, nullptr, out0, x, MROWS_, NOUT_, IND_);
}

// Round 11
// 244.032 us; speedup vs baseline: 1.0868x; 1.0868x over previous
//
#include <hip/hip_runtime.h>

typedef unsigned short u16;
typedef __attribute__((ext_vector_type(4))) unsigned short u16x4;
typedef __attribute__((ext_vector_type(8))) unsigned short u16x8;
typedef __attribute__((ext_vector_type(8))) __bf16 bf16x8;
typedef __attribute__((ext_vector_type(4))) float f32x4;

#define SLEN_ 2048
#define BSZ_ 8
#define NH_ 16
#define DH_ 64
#define IND_ 1024
#define MROWS_ (SLEN_*BSZ_)   // 16384
#define NQKV_ (NH_*3*DH_)     // 3072
#define NOUT_ (NH_*DH_)       // 1024
#define NT_ 16                // K-tiles of 64 (K=1024)

__device__ __forceinline__ float b2f(u16 u) {
    return __uint_as_float(((unsigned)u) << 16);
}
__device__ __forceinline__ u16 f2b(float f) {
    unsigned u = __float_as_uint(f);
    u = u + 0x7FFFu + ((u >> 16) & 1u);   // RNE
    return (u16)(u >> 16);
}

#define GLOAD_LDS16(g, l) __builtin_amdgcn_global_load_lds( \
    (const __attribute__((address_space(1))) unsigned int*)(g), \
    (__attribute__((address_space(3))) unsigned int*)(l), 16, 0, 0)

// swizzled LDS byte offset for [64][64] bf16 tiles (row stride 128 B)
#define TI(r, c) ((((r) << 7) + ((c) << 1)) ^ (((r) & 7) << 4))

// ---------------- cast fp32 weights -> bf16 ----------------
__global__ __launch_bounds__(256) void cast_weights(
        const float* __restrict__ wq, const float* __restrict__ wo,
        u16* __restrict__ wqb, u16* __restrict__ wob)
{
    int i = blockIdx.x * 256 + threadIdx.x;
    const int NQ4 = NQKV_ * IND_ / 4;
    float4 v;
    u16* dst;
    if (i < NQ4) { v = ((const float4*)wq)[i]; dst = wqb + (size_t)i * 4; }
    else { int j = i - NQ4; v = ((const float4*)wo)[j]; dst = wob + (size_t)j * 4; }
    u16x4 o;
    o[0] = f2b(v.x); o[1] = f2b(v.y); o[2] = f2b(v.z); o[3] = f2b(v.w);
    *(u16x4*)dst = o;
}

// ---------------- LayerNorm -> bf16 ----------------
__global__ __launch_bounds__(256) void ln_kernel(
        const float* __restrict__ x, const float* __restrict__ g,
        const float* __restrict__ bt, u16* __restrict__ h)
{
    int row = blockIdx.x, tid = threadIdx.x;
    const float4 v = ((const float4*)(x + (size_t)row * IND_))[tid];
    float s  = v.x + v.y + v.z + v.w;
    float s2 = v.x*v.x + v.y*v.y + v.z*v.z + v.w*v.w;
    #pragma unroll
    for (int m = 1; m < 64; m <<= 1) { s += __shfl_xor(s, m); s2 += __shfl_xor(s2, m); }
    __shared__ float sh[8];
    int w = tid >> 6, l = tid & 63;
    if (l == 0) { sh[w] = s; sh[4 + w] = s2; }
    __syncthreads();
    s  = sh[0] + sh[1] + sh[2] + sh[3];
    s2 = sh[4] + sh[5] + sh[6] + sh[7];
    float mu   = s * (1.f / IND_);
    float var  = s2 * (1.f / IND_) - mu * mu;
    float rstd = rsqrtf(var + 1e-5f);
    float4 gg = ((const float4*)g)[tid];
    float4 bb = ((const float4*)bt)[tid];
    u16x4 o;
    o[0] = f2b((v.x - mu) * rstd * gg.x + bb.x);
    o[1] = f2b((v.y - mu) * rstd * gg.y + bb.y);
    o[2] = f2b((v.z - mu) * rstd * gg.z + bb.z);
    o[3] = f2b((v.w - mu) * rstd * gg.w + bb.w);
    ((u16x4*)(h + (size_t)row * IND_))[tid] = o;
}

// ---------------- 256x256 bf16 GEMM, C[M,N] = A[M,K]*B[N,K]^T, BK=64 ----------------
// (round-5 schedule: session best 114.5us, MfmaUtil 37.7%, 0 conflicts.
//  Locality XCD map + ks-half lookahead pipeline.)
template<int MODE>
__global__ __launch_bounds__(512, 2) void gemm256(
        const u16* __restrict__ A, const u16* __restrict__ Bm,
        u16* __restrict__ Cb, float* __restrict__ Cf, const float* __restrict__ X,
        int M, int N, int K)
{
    __shared__ char smem[131072];   // [buf][A 32KB | B 32KB]

    const int tid = threadIdx.x;
    const int w = tid >> 6, l = tid & 63;
    const int wmi = w >> 2, wni = w & 3;
    const int fr = l & 15, fq = l >> 4;

    const int h = blockIdx.y * gridDim.x + blockIdx.x;
    const int xcd = h & 7, i = h >> 3;
    const int bm = xcd * 8 + (i & 7);
    const int bn = i >> 3;

    const int sr = l >> 3;
    const int sc = ((l & 7) ^ sr) * 8;
    const u16* ga = A  + (size_t)(bm * 256 + w * 8 + sr) * K + sc;
    const u16* gb = Bm + (size_t)(bn * 256 + w * 8 + sr) * K + sc;
    char* lA = smem + w * 1024;
    char* lB = smem + 32768 + w * 1024;
    const size_t K64 = (size_t)K * 64;

#define STAGE(t, bufb) { \
    const u16* gat = ga + (t) * 64; const u16* gbt = gb + (t) * 64; \
    char* la = lA + (bufb) * 65536; char* lb = lB + (bufb) * 65536; \
    GLOAD_LDS16(gat,            la);            \
    GLOAD_LDS16(gat + K64,      la + 8192);     \
    GLOAD_LDS16(gat + 2 * K64,  la + 16384);    \
    GLOAD_LDS16(gat + 3 * K64,  la + 24576);    \
    GLOAD_LDS16(gbt,            lb);            \
    GLOAD_LDS16(gbt + K64,      lb + 8192);     \
    GLOAD_LDS16(gbt + 2 * K64,  lb + 16384);    \
    GLOAD_LDS16(gbt + 3 * K64,  lb + 24576);    \
}

    const int cswz = (fr & 7) << 4;
    const int c0 = (fq * 16) ^ cswz;
    const int c1 = (64 + fq * 16) ^ cswz;
    const char* rdA = smem + (wmi * 128 + fr) * 128;
    const char* rdB = smem + 32768 + (wni * 64 + fr) * 128;

#define RD_FRAGS(dstA, dstB, base_off, cc) { \
    const char* bA_ = rdA + (base_off); const char* bB_ = rdB + (base_off); \
    _Pragma("unroll") for (int m_ = 0; m_ < 8; m_++) \
        dstA[m_] = *(const bf16x8*)(bA_ + m_ * 2048 + (cc)); \
    _Pragma("unroll") for (int n_ = 0; n_ < 4; n_++) \
        dstB[n_] = *(const bf16x8*)(bB_ + n_ * 2048 + (cc)); \
}

#define MFMA32(srcA, srcB) { \
    _Pragma("unroll") for (int m_ = 0; m_ < 8; m_++) \
        _Pragma("unroll") for (int n_ = 0; n_ < 4; n_++) \
            acc[m_][n_] = __builtin_amdgcn_mfma_f32_16x16x32_bf16(srcA[m_], srcB[n_], acc[m_][n_], 0, 0, 0); \
}

    f32x4 acc[8][4] = {};
    bf16x8 fsA_A[8], fsA_B[4];
    bf16x8 fsB_A[8], fsB_B[4];

    STAGE(0, 0);
    STAGE(1, 1);
    asm volatile("s_waitcnt vmcnt(8)" ::: "memory");
    __builtin_amdgcn_s_barrier();
    RD_FRAGS(fsA_A, fsA_B, 0, c0);
    asm volatile("s_waitcnt lgkmcnt(0)" ::: "memory");
    __builtin_amdgcn_sched_barrier(0);

    #pragma unroll 1
    for (int t = 0; t < NT_; t++) {
        const int cur = (t & 1) * 65536;
        const int nxt = ((t + 1) & 1) * 65536;
        RD_FRAGS(fsB_A, fsB_B, cur, c1);
        __builtin_amdgcn_s_setprio(1);
        MFMA32(fsA_A, fsA_B);
        __builtin_amdgcn_s_setprio(0);
        asm volatile("s_waitcnt lgkmcnt(0)" ::: "memory");
        __builtin_amdgcn_sched_barrier(0);
        __builtin_amdgcn_s_barrier();
        if (t + 2 < NT_) STAGE(t + 2, t & 1);
        if (t < NT_ - 2) asm volatile("s_waitcnt vmcnt(8)" ::: "memory");
        else             asm volatile("s_waitcnt vmcnt(0)" ::: "memory");
        __builtin_amdgcn_s_barrier();
        if (t < NT_ - 1) RD_FRAGS(fsA_A, fsA_B, nxt, c0);
        __builtin_amdgcn_s_setprio(1);
        MFMA32(fsB_A, fsB_B);
        __builtin_amdgcn_s_setprio(0);
        asm volatile("s_waitcnt lgkmcnt(0)" ::: "memory");
        __builtin_amdgcn_sched_barrier(0);
        __builtin_amdgcn_s_barrier();
    }
#undef STAGE
#undef RD_FRAGS
#undef MFMA32

    #pragma unroll
    for (int m = 0; m < 8; m++)
        #pragma unroll
        for (int r = 0; r < 4; r++) {
            int row = bm * 256 + wmi * 128 + m * 16 + fq * 4 + r;
            #pragma unroll
            for (int n = 0; n < 4; n++) {
                int col = bn * 256 + wni * 64 + n * 16 + fr;
                float vv = acc[m][n][r];
                if (MODE == 0) {
                    Cb[(size_t)row * N + col] = f2b(vv);
                } else {
                    size_t idx = (size_t)row * N + col;
                    Cf[idx] = vv + X[idx];
                }
            }
        }
}

// ---------------- scanS: S_c = K^T V per chunk (grid 4096 = n*128 + bh) ----------------
__global__ __launch_bounds__(256) void scanS(
        const u16* __restrict__ qkv, u16* __restrict__ Sbuf)
{
    __shared__ u16 Kt_l[4096], Vt_l[4096];

    const int blk = blockIdx.x;
    const int bh = blk & 127, n = blk >> 7;
    const int b = bh >> 4, hh = bh & 15;
    const int tid = threadIdx.x;
    const int w = tid >> 6, l = tid & 63;
    const int fr = l & 15, fq = l >> 4;

    // staging: w0 = k rows (elu+norm, transposed), w1/w2 = v halves (transposed)
    if (w == 0) {
        const u16* g0 = qkv + ((size_t)(n * 64 + l) * BSZ_ + b) * NQKV_ + hh * 192 + 64;
        u16x8 pre[8];
        #pragma unroll
        for (int j = 0; j < 8; j++) pre[j] = *(const u16x8*)(g0 + j * 8);
        float f[64];
        #pragma unroll
        for (int j = 0; j < 8; j++)
            #pragma unroll
            for (int m = 0; m < 8; m++) {
                float x = b2f(pre[j][m]);
                f[j * 8 + m] = x > 0.f ? x + 1.f : __expf(x);
            }
        float s = 0.f;
        #pragma unroll
        for (int i = 0; i < 64; i++) s += f[i];
        float inv = 1.f / (s + 1e-5f);
        #pragma unroll
        for (int j = 0; j < 8; j++)
            #pragma unroll
            for (int m = 0; m < 8; m++)
                *(u16*)((char*)Kt_l + TI(j * 8 + m, l)) = f2b(f[j * 8 + m] * inv);
    } else if (w <= 2) {
        const u16* g0 = qkv + ((size_t)(n * 64 + l) * BSZ_ + b) * NQKV_ + hh * 192 + 128 + (w - 1) * 32;
        int e0 = (w - 1) * 32;
        u16x8 pre[4];
        #pragma unroll
        for (int j = 0; j < 4; j++) pre[j] = *(const u16x8*)(g0 + j * 8);
        #pragma unroll
        for (int j = 0; j < 4; j++)
            #pragma unroll
            for (int m = 0; m < 8; m++)
                *(u16*)((char*)Vt_l + TI(e0 + j * 8 + m, l)) = pre[j][m];
    }
    __syncthreads();

    // S[d][e] = Kt[d] . Vt[e]
    f32x4 aS2[4] = {};
    bf16x8 akt[2];
    #pragma unroll
    for (int ks = 0; ks < 2; ks++)
        akt[ks] = *(const bf16x8*)((const char*)Kt_l + TI(w * 16 + fr, ks * 32 + fq * 8));
    #pragma unroll
    for (int jt = 0; jt < 4; jt++)
        #pragma unroll
        for (int ks = 0; ks < 2; ks++) {
            bf16x8 bv = *(const bf16x8*)((const char*)Vt_l + TI(jt * 16 + fr, ks * 32 + fq * 8));
            aS2[jt] = __builtin_amdgcn_mfma_f32_16x16x32_bf16(akt[ks], bv, aS2[jt], 0, 0, 0);
        }

    u16* Sg = Sbuf + ((size_t)bh * 32 + n) * 4096;
    #pragma unroll
    for (int jt = 0; jt < 4; jt++)
        #pragma unroll
        for (int r = 0; r < 4; r++)
            Sg[(w * 16 + fq * 4 + r) * 64 + jt * 16 + fr] = f2b(aS2[jt][r]);
}

// ---------------- scanB: exclusive prefix over chunks (in-place bf16) ----------------
__global__ __launch_bounds__(256) void scanB(
        u16* __restrict__ Sbuf, const float* __restrict__ state, float* __restrict__ wfin)
{
    const int blk = blockIdx.x;
    const int bh = blk >> 2;
    const int e0 = (blk & 3) * 1024 + threadIdx.x * 4;
    float4 acc = *(const float4*)(state + (size_t)bh * 4096 + e0);
    u16* Sp = Sbuf + (size_t)bh * 32 * 4096 + e0;
    #pragma unroll
    for (int nn = 0; nn < 32; nn++) {
        u16x4 s = *(const u16x4*)(Sp + nn * 4096);
        u16x4 p;
        p[0] = f2b(acc.x); p[1] = f2b(acc.y); p[2] = f2b(acc.z); p[3] = f2b(acc.w);
        *(u16x4*)(Sp + nn * 4096) = p;
        acc.x += b2f(s[0]); acc.y += b2f(s[1]);
        acc.z += b2f(s[2]); acc.w += b2f(s[3]);
    }
    *(float4*)(wfin + (size_t)bh * 4096 + e0) = acc;
}

// ---------------- scanO: O = tril(K·Q^T)·V + Q·W_prefix (grid 4096) ----------------
__global__ __launch_bounds__(256) void scanO(
        const u16* __restrict__ qkv, const u16* __restrict__ Sbuf, u16* __restrict__ obf)
{
    __shared__ u16 Q_l[4096], K_l[4096], Vt_l[4096], P_l[4096], W_l[4096];

    const int blk = blockIdx.x;
    const int bh = blk & 127, n = blk >> 7;
    const int b = bh >> 4, hh = bh & 15;
    const int tid = threadIdx.x;
    const int w = tid >> 6, l = tid & 63;
    const int fr = l & 15, fq = l >> 4;

    // issue q/k/v loads first (w0=q, w1=k, w2/w3=v halves)
    int goff = (w == 0) ? 0 : (w == 1) ? 64 : (w == 2) ? 128 : 160;
    const u16* g0 = qkv + ((size_t)(n * 64 + l) * BSZ_ + b) * NQKV_ + hh * 192 + goff;
    u16x8 pre[8];
    if (w < 2) {
        #pragma unroll
        for (int j = 0; j < 8; j++) pre[j] = *(const u16x8*)(g0 + j * 8);
    } else {
        #pragma unroll
        for (int j = 0; j < 4; j++) pre[j] = *(const u16x8*)(g0 + j * 8);
    }

    // W_l fill from bf16 prefix [d][e] -> swizzled [e][d] (overlaps loads)
    const u16* Wp = Sbuf + ((size_t)bh * 32 + n) * 4096;
    #pragma unroll
    for (int k2 = 0; k2 < 4; k2++) {
        int g = tid * 4 + k2 * 1024;
        u16x4 s = *(const u16x4*)(Wp + g);
        int d = g >> 6, e = g & 63;
        #pragma unroll
        for (int i2 = 0; i2 < 4; i2++)
            *(u16*)((char*)W_l + TI(e + i2, d)) = s[i2];
    }

    // process staged regs -> LDS
    if (w < 2) {
        float f[64];
        #pragma unroll
        for (int j = 0; j < 8; j++)
            #pragma unroll
            for (int m = 0; m < 8; m++) {
                float x = b2f(pre[j][m]);
                f[j * 8 + m] = x > 0.f ? x + 1.f : __expf(x);
            }
        float s = 0.f;
        #pragma unroll
        for (int i = 0; i < 64; i++) s += f[i];
        float inv = 1.f / (s + 1e-5f);
        u16* dst = (w == 0) ? Q_l : K_l;
        #pragma unroll
        for (int j = 0; j < 8; j++) {
            u16x8 o;
            #pragma unroll
            for (int m = 0; m < 8; m++) o[m] = f2b(f[j * 8 + m] * inv);
            *(u16x8*)((char*)dst + TI(l, j * 8)) = o;
        }
    } else {
        int e0 = (w == 2) ? 0 : 32;
        #pragma unroll
        for (int j = 0; j < 4; j++)
            #pragma unroll
            for (int m = 0; m < 8; m++)
                *(u16*)((char*)Vt_l + TI(e0 + j * 8 + m, l)) = pre[j][m];
    }
    __syncthreads();

    // St = K·Q^T (out rows s = w*16.., cols t); masked P[t][s] -> P_l
    f32x4 aS[4] = {};
    bf16x8 aK[2];
    #pragma unroll
    for (int ks = 0; ks < 2; ks++)
        aK[ks] = *(const bf16x8*)((const char*)K_l + TI(w * 16 + fr, ks * 32 + fq * 8));
    #pragma unroll
    for (int jt = 0; jt < 4; jt++)
        #pragma unroll
        for (int ks = 0; ks < 2; ks++) {
            bf16x8 bq = *(const bf16x8*)((const char*)Q_l + TI(jt * 16 + fr, ks * 32 + fq * 8));
            aS[jt] = __builtin_amdgcn_mfma_f32_16x16x32_bf16(aK[ks], bq, aS[jt], 0, 0, 0);
        }
    #pragma unroll
    for (int jt = 0; jt < 4; jt++) {
        int t = jt * 16 + fr;
        int s0 = w * 16 + fq * 4;
        u16 e0 = (s0 + 0 <= t) ? f2b(aS[jt][0]) : (u16)0;
        u16 e1 = (s0 + 1 <= t) ? f2b(aS[jt][1]) : (u16)0;
        u16 e2 = (s0 + 2 <= t) ? f2b(aS[jt][2]) : (u16)0;
        u16 e3 = (s0 + 3 <= t) ? f2b(aS[jt][3]) : (u16)0;
        uint2 pkk;
        pkk.x = (unsigned)e0 | ((unsigned)e1 << 16);
        pkk.y = (unsigned)e2 | ((unsigned)e3 << 16);
        *(uint2*)((char*)P_l + TI(t, s0)) = pkk;
    }
    __syncthreads();

    // O = P·V + Q·W_prefix (rows t = w*16..)
    f32x4 aO[4] = {};
    bf16x8 ap[2], aq2[2];
    #pragma unroll
    for (int ks = 0; ks < 2; ks++) {
        ap[ks]  = *(const bf16x8*)((const char*)P_l + TI(w * 16 + fr, ks * 32 + fq * 8));
        aq2[ks] = *(const bf16x8*)((const char*)Q_l + TI(w * 16 + fr, ks * 32 + fq * 8));
    }
    #pragma unroll
    for (int jt = 0; jt < 4; jt++) {
        #pragma unroll
        for (int ks = 0; ks < 2; ks++) {
            bf16x8 bv = *(const bf16x8*)((const char*)Vt_l + TI(jt * 16 + fr, ks * 32 + fq * 8));
            aO[jt] = __builtin_amdgcn_mfma_f32_16x16x32_bf16(ap[ks], bv, aO[jt], 0, 0, 0);
        }
        #pragma unroll
        for (int ks = 0; ks < 2; ks++) {
            bf16x8 bw = *(const bf16x8*)((const char*)W_l + TI(jt * 16 + fr, ks * 32 + fq * 8));
            aO[jt] = __builtin_amdgcn_mfma_f32_16x16x32_bf16(aq2[ks], bw, aO[jt], 0, 0, 0);
        }
    }
    __syncthreads();

    // stage O into P_l (rows t, cols e)
    #pragma unroll
    for (int jt = 0; jt < 4; jt++)
        #pragma unroll
        for (int r = 0; r < 4; r++)
            *(u16*)((char*)P_l + TI(w * 16 + fq * 4 + r, jt * 16 + fr)) = f2b(aO[jt][r]);
    __syncthreads();

    // coalesced O global write
    {
        int t = tid >> 2, seg = tid & 3;
        u16x8 o1 = *(const u16x8*)((const char*)P_l + TI(t, seg * 16));
        u16x8 o2 = *(const u16x8*)((const char*)P_l + TI(t, seg * 16 + 8));
        u16* gd = obf + ((size_t)(n * 64 + t) * BSZ_ + b) * NOUT_ + hh * 64 + seg * 16;
        *(u16x8*)(gd) = o1;
        *(u16x8*)(gd + 8) = o2;
    }
}

extern "C" void kernel_launch(void* const* d_in, const int* in_sizes, int n_in,
                              void* d_out, int out_size, void* d_ws, size_t ws_size,
                              hipStream_t stream) {
    const float* x     = (const float*)d_in[0];
    const float* state = (const float*)d_in[1];
    const float* wqkv  = (const float*)d_in[2];
    const float* wout  = (const float*)d_in[3];
    const float* gamma = (const float*)d_in[4];
    const float* beta  = (const float*)d_in[5];

    float* out0 = (float*)d_out;
    float* wfin = (float*)d_out + (size_t)MROWS_ * IND_;

    char* ws = (char*)d_ws;
    u16* qkv_bf = (u16*)ws;                                   // 96 MiB
    u16* h_bf   = (u16*)(ws + 100663296);                     // 32 MiB (o_bf reuse)
    u16* o_bf   = h_bf;
    u16* wq_bf  = (u16*)(ws + 134217728);                     // 6 MiB
    u16* wo_bf  = (u16*)(ws + 140509184);                     // 2 MiB
    u16* S_bf   = (u16*)(ws + 142606336);                     // 32 MiB (S / prefix)

    cast_weights<<<4096, 256, 0, stream>>>(wqkv, wout, wq_bf, wo_bf);
    ln_kernel<<<MROWS_, 256, 0, stream>>>(x, gamma, beta, h_bf);
    dim3 g1(MROWS_ / 256, NQKV_ / 256);   // 64 x 12 = 768 blocks
    gemm256<0><<<g1, 512, 0, stream>>>(h_bf, wq_bf, qkv_bf, nullptr, nullptr, MROWS_, NQKV_, IND_);
    scanS<<<4096, 256, 0, stream>>>(qkv_bf, S_bf);
    scanB<<<512, 256, 0, stream>>>(S_bf, state, wfin);
    scanO<<<4096, 256, 0, stream>>>(qkv_bf, S_bf, o_bf);
    dim3 g2(MROWS_ / 256, NOUT_ / 256);   // 64 x 4 = 256 blocks
    gemm256<1><<<g2, 512, 0, stream>>>(o_bf, wo_bf, nullptr, out0, x, MROWS_, NOUT_, IND_);
}